// Round 1
// baseline (1557.188 us; speedup 1.0000x reference)
//
#include <hip/hip_runtime.h>

#define HIDDEN 3584
#define NHEADS 32
#define NKV 4
#define HD 128
#define BB 2
#define SS 2048
#define LDPP 68     // padded u16 row stride for P^T LDS tile (136B)

typedef unsigned short u16;
typedef unsigned int   u32;
typedef __bf16 bf16x8 __attribute__((ext_vector_type(8)));
typedef float  f32x4  __attribute__((ext_vector_type(4)));

__device__ __forceinline__ f32x4 mfma16(bf16x8 a, bf16x8 b, f32x4 c) {
    return __builtin_amdgcn_mfma_f32_16x16x32_bf16(a, b, c, 0, 0, 0);
}

// round-to-nearest-even float->bf16 (no NaN inputs in this problem)
__device__ __forceinline__ u16 bf16_rne(float x) {
    u32 u = __float_as_uint(x);
    return (u16)((u + 0x7FFFu + ((u >> 16) & 1u)) >> 16);
}

// split fp32 pair into packed hi-bf16 pair and lo-bf16 pair (truncation split, rel err ~2^-16)
__device__ __forceinline__ void split_pair(float x0, float x1, u32 &hp, u32 &lp) {
    u32 u0 = __float_as_uint(x0), u1 = __float_as_uint(x1);
    hp = (u0 >> 16) | (u1 & 0xFFFF0000u);
    float r0 = x0 - __uint_as_float(u0 & 0xFFFF0000u);
    float r1 = x1 - __uint_as_float(u1 & 0xFFFF0000u);
    lp = (__float_as_uint(r0) >> 16) | (__float_as_uint(r1) & 0xFFFF0000u);
}

// async global->LDS, 16B per lane; dst is wave-uniform base, lane i lands at dst + i*16B
__device__ __forceinline__ void gld16(const u16* g, const u16* l) {
    __builtin_amdgcn_global_load_lds(
        (const __attribute__((address_space(1))) void*)(uintptr_t)(const void*)g,
        (__attribute__((address_space(3))) void*)(uintptr_t)(const void*)l,
        16, 0, 0);
}

// ---------------- K0: RoPE cos/sin tables [S][64] ----------------
__global__ void k_rope(float* __restrict__ ct, float* __restrict__ st) {
    int i = blockIdx.x * 256 + threadIdx.x;   // 2048*64 entries
    int s = i >> 6, j = i & 63;
    float invf = exp2f(-(float)j * (19.931568569324174f / 64.0f));
    float a = (float)s * invf;
    ct[i] = cosf(a);
    st[i] = sinf(a);
}

// ---------------- K0b: fp32 -> (hi,lo) bf16 plane split, 4 elems/thread ----------------
__global__ __launch_bounds__(256) void k_split4(
    const float* __restrict__ in, u16* __restrict__ hi, u16* __restrict__ lo, int n4)
{
    int i = blockIdx.x * 256 + threadIdx.x;
    if (i >= n4) return;
    float4 v = ((const float4*)in)[i];
    u32 h0, l0, h1, l1;
    split_pair(v.x, v.y, h0, l0);
    split_pair(v.z, v.w, h1, l1);
    ((uint2*)hi)[i] = make_uint2(h0, h1);
    ((uint2*)lo)[i] = make_uint2(l0, l1);
}

// ---------------- K1: fused QKV projection + RoPE (pre-split bf16 inputs) ----------------
__global__ __launch_bounds__(256) void k_qkv(
    const u16* __restrict__ Xh, const u16* __restrict__ Xl,
    const u16* __restrict__ Wh, const u16* __restrict__ Wl,
    const float* __restrict__ ct, const float* __restrict__ st,
    u16* __restrict__ Qh, u16* __restrict__ Ql,
    u16* __restrict__ Kh, u16* __restrict__ Kl,
    u16* __restrict__ Vt)
{
    __shared__ u16 sm[16640];   // 4 planes x [128][32] = 16384 u16; V-transpose reuse needs 16640

    const int tid  = threadIdx.x;
    const int w    = tid >> 6;
    const int lane = tid & 63;
    const int quad = lane >> 4;
    const int l16  = lane & 15;
    const int ntb  = blockIdx.x;
    const int m0   = blockIdx.y * 128;
    const int n0   = ntb * 128;

    const u16* pb;
    if      (w == 0) pb = Xh + (size_t)m0 * HIDDEN;
    else if (w == 1) pb = Xl + (size_t)m0 * HIDDEN;
    else if (w == 2) pb = Wh + (size_t)n0 * HIDDEN;
    else             pb = Wl + (size_t)n0 * HIDDEN;
    const u16* gsrc = pb + (size_t)(lane >> 2) * HIDDEN + (lane & 3) * 8;
    u16* lplane = sm + w * 4096;

    const f32x4 zero4 = {0.f, 0.f, 0.f, 0.f};
    f32x4 acc[2][8];
    #pragma unroll
    for (int i = 0; i < 2; i++)
        #pragma unroll
        for (int j = 0; j < 8; j++) acc[i][j] = zero4;

    for (int kk = 0; kk < HIDDEN; kk += 32) {
        __syncthreads();
        #pragma unroll
        for (int c = 0; c < 8; c++)
            gld16(gsrc + (size_t)c * 16 * HIDDEN + kk, lplane + c * 512);
        __syncthreads();

        bf16x8 ah[2], al[2];
        #pragma unroll
        for (int mt = 0; mt < 2; mt++) {
            int rr = w * 32 + mt * 16 + l16;
            ah[mt] = *(const bf16x8*)&sm[rr * 32 + quad * 8];
            al[mt] = *(const bf16x8*)&sm[4096 + rr * 32 + quad * 8];
        }
        #pragma unroll
        for (int nt = 0; nt < 8; nt++) {
            int rr = nt * 16 + l16;
            bf16x8 bh = *(const bf16x8*)&sm[8192  + rr * 32 + quad * 8];
            bf16x8 bl = *(const bf16x8*)&sm[12288 + rr * 32 + quad * 8];
            #pragma unroll
            for (int mt = 0; mt < 2; mt++) {
                acc[mt][nt] = mfma16(ah[mt], bh, acc[mt][nt]);
                acc[mt][nt] = mfma16(ah[mt], bl, acc[mt][nt]);
                acc[mt][nt] = mfma16(al[mt], bh, acc[mt][nt]);
            }
        }
    }

    const int b  = m0 / SS;
    const int s0 = m0 % SS;
    int region;
    if (ntb < 32)      region = 0;
    else if (ntb < 36) region = 1;
    else               region = 2;

    if (region < 2) {
        u16* dH = (region == 0) ? Qh : Kh;
        u16* dL = (region == 0) ? Ql : Kl;
        const int head   = (region == 0) ? ntb : (ntb - 32);
        const int nheads = (region == 0) ? NHEADS : NKV;
        const float qsc  = (region == 0) ? 0.08838834764831845f : 1.0f;
        #pragma unroll
        for (int mt = 0; mt < 2; mt++) {
            #pragma unroll
            for (int r = 0; r < 4; r++) {
                int s = s0 + w * 32 + mt * 16 + quad * 4 + r;
                const float* cr = ct + s * 64;
                const float* sr = st + s * 64;
                #pragma unroll
                for (int nt = 0; nt < 8; nt++) {
                    int d  = nt * 16 + l16;
                    int jj = (nt & 3) * 16 + l16;
                    float c = cr[jj], sn = sr[jj];
                    float v = acc[mt][nt][r];
                    float p = acc[mt][nt ^ 4][r];
                    float o = (nt < 4) ? (v * c - p * sn) : (v * c + p * sn);
                    o *= qsc;
                    size_t idx = ((size_t)(b * nheads + head) * SS + s) * HD + d;
                    u32 u = __float_as_uint(o);
                    dH[idx] = (u16)(u >> 16);
                    float rr2 = o - __uint_as_float(u & 0xFFFF0000u);
                    dL[idx] = (u16)(__float_as_uint(rr2) >> 16);
                }
            }
        }
    } else {
        __syncthreads();
        u16* tb = sm;   // 128 x 130
        #pragma unroll
        for (int mt = 0; mt < 2; mt++)
            #pragma unroll
            for (int nt = 0; nt < 8; nt++)
                #pragma unroll
                for (int r = 0; r < 4; r++) {
                    int rl = w * 32 + mt * 16 + quad * 4 + r;
                    int d  = nt * 16 + l16;
                    tb[rl * 130 + d] = bf16_rne(acc[mt][nt][r]);
                }
        __syncthreads();
        const int hv = ntb - 36;
        const int d = tid >> 1, half = tid & 1;
        u16* dst = Vt + ((size_t)(b * NKV + hv) * HD + d) * SS + s0 + half * 64;
        #pragma unroll
        for (int j0 = 0; j0 < 64; j0 += 4) {
            ushort4 vv;
            vv.x = tb[(half * 64 + j0 + 0) * 130 + d];
            vv.y = tb[(half * 64 + j0 + 1) * 130 + d];
            vv.z = tb[(half * 64 + j0 + 2) * 130 + d];
            vv.w = tb[(half * 64 + j0 + 3) * 130 + d];
            *(ushort4*)(dst + j0) = vv;
        }
    }
}

// ---------------- K2: flash attention v3 — transposed scores, LDS-staged KV, 1 barrier/iter ----------------
// Pipelined K-loop: at iter top, one __syncthreads() drains the gld16s issued a full compute
// phase earlier (other LDS parity); then issue next iter's K/V loads; then compute from current parity.
// S^T = K·Q^T; softmax per lane-column; P^T wave-private LDS; O^T = V^T·P^T.
// grid: (S/128, NHEADS, B), block 256. Wave w owns query rows [w*32, w*32+32). 64 keys/iter.
__global__ __launch_bounds__(256, 1) void k_attn(
    const u16* __restrict__ Qh, const u16* __restrict__ Ql,
    const u16* __restrict__ Kh, const u16* __restrict__ Kl,
    const u16* __restrict__ Vt, u16* __restrict__ Ao_h, u16* __restrict__ Ao_l)
{
    // parity p at ls + p*24576 (u16 units): Khi 4x[64][32] | Klo 4x[64][32] | V 2x[128][32]
    // P^T at ls + 49152 + w*2176: [32 q][64 key] stride LDPP
    __shared__ u16 ls[57856];   // 115712 B

    const int tid  = threadIdx.x;
    const int w    = tid >> 6;
    const int lane = tid & 63;
    const int quad = lane >> 4;
    const int l16  = lane & 15;
    const int q0 = blockIdx.x * 128, h = blockIdx.y, b = blockIdx.z, hv = h >> 3;

    const u16* qbh = Qh + ((size_t)(b * NHEADS + h) * SS + q0) * HD;
    const u16* qbl = Ql + ((size_t)(b * NHEADS + h) * SS + q0) * HD;
    const u16* kbh = Kh + (size_t)(b * NKV + hv) * SS * HD;
    const u16* kbl = Kl + (size_t)(b * NKV + hv) * SS * HD;
    const u16* vb  = Vt + (size_t)(b * NKV + hv) * HD * SS;

    // Q fragments resident (B-operand of S^T: lane l16 = q-row, k = quad*8+j dims)
    bf16x8 qfh[2][4], qfl[2][4];
    #pragma unroll
    for (int qt = 0; qt < 2; qt++) {
        int row = w * 32 + qt * 16 + l16;
        #pragma unroll
        for (int c = 0; c < 4; c++) {
            qfh[qt][c] = *(const bf16x8*)(qbh + (size_t)row * HD + c * 32 + quad * 8);
            qfl[qt][c] = *(const bf16x8*)(qbl + (size_t)row * HD + c * 32 + quad * 8);
        }
    }

    const f32x4 zero4 = {0.f, 0.f, 0.f, 0.f};
    f32x4 ot[8][2];              // O^T accum: row=dim(quad*4+r within ntd tile), col=q(l16)
    #pragma unroll
    for (int i = 0; i < 8; i++)
        #pragma unroll
        for (int j = 0; j < 2; j++) ot[i][j] = zero4;
    float mr[2] = {-INFINITY, -INFINITY}, lr[2] = {0.f, 0.f};   // per-lane: q = qt*16+l16

    u16* pw = ls + 49152 + w * 2176;

    // stage 12 gld16 (1KB each) for iteration `it` into parity it&1; wave w covers g = w*12..w*12+11
    auto stage = [&](int it) {
        u16* base = ls + (it & 1) * 24576;
        int kt64 = it * 64;
        #pragma unroll
        for (int j = 0; j < 12; j++) {
            int g = w * 12 + j;          // wave-uniform
            const u16* gp; u16* lp;
            if (g < 32) {                // K planes: 2 planes x 4 chunks x 4 segs
                int plane = g >> 4, c = (g >> 2) & 3, seg = g & 3;
                const u16* kb = plane ? kbl : kbh;
                gp = kb + (size_t)(kt64 + seg * 16 + (lane >> 2)) * HD + c * 32 + (lane & 3) * 8;
                lp = base + plane * 8192 + c * 2048 + seg * 512 + lane * 8;
            } else {                     // V: 2 key-chunks x 8 segs of [16 d][32 k]
                int gg = g - 32, ks = gg >> 3, seg = gg & 7;
                gp = vb + (size_t)(seg * 16 + (lane >> 2)) * SS + kt64 + ks * 32 + (lane & 3) * 8;
                lp = base + 16384 + ks * 4096 + seg * 512 + lane * 8;
            }
            gld16(gp, lp);
        }
    };

    stage(0);

    for (int it = 0; it < SS / 64; it++) {
        __syncthreads();                 // drains own gld16s for iter `it`; syncs LDS visibility
        if (it + 1 < SS / 64) stage(it + 1);

        const u16* cur = ls + (it & 1) * 24576;

        // ---- scores: A = K fragment from LDS (lane l16 = key row within 16-subtile) ----
        f32x4 scr[4][2];                 // S^T: [key-subtile nt][q-tile qt]
        #pragma unroll
        for (int i = 0; i < 4; i++)
            #pragma unroll
            for (int j = 0; j < 2; j++) scr[i][j] = zero4;

        #pragma unroll
        for (int c = 0; c < 4; c++) {
            #pragma unroll
            for (int nt = 0; nt < 4; nt++) {
                int off = c * 2048 + (nt * 16 + l16) * 32 + quad * 8;
                bf16x8 kh8 = *(const bf16x8*)&cur[off];
                bf16x8 kl8 = *(const bf16x8*)&cur[8192 + off];
                #pragma unroll
                for (int qt = 0; qt < 2; qt++) {
                    scr[nt][qt] = mfma16(kh8, qfh[qt][c], scr[nt][qt]);
                    scr[nt][qt] = mfma16(kh8, qfl[qt][c], scr[nt][qt]);
                    scr[nt][qt] = mfma16(kl8, qfh[qt][c], scr[nt][qt]);
                }
            }
        }

        // ---- online softmax: stats per lane column (q = qt*16+l16) ----
        float alpha[2];
        #pragma unroll
        for (int qt = 0; qt < 2; qt++) {
            f32x4 m4 = scr[0][qt];
            #pragma unroll
            for (int nt = 1; nt < 4; nt++) m4 = __builtin_elementwise_max(m4, scr[nt][qt]);
            float rm = fmaxf(fmaxf(m4[0], m4[1]), fmaxf(m4[2], m4[3]));
            rm = fmaxf(rm, __shfl_xor(rm, 16));
            rm = fmaxf(rm, __shfl_xor(rm, 32));
            float mn = fmaxf(mr[qt], rm);
            float al = __expf(mr[qt] - mn);
            mr[qt] = mn;
            float rs = 0.f;
            #pragma unroll
            for (int nt = 0; nt < 4; nt++)
                #pragma unroll
                for (int r = 0; r < 4; r++) {
                    float p = __expf(scr[nt][qt][r] - mn);
                    scr[nt][qt][r] = p;
                    rs += p;
                }
            rs += __shfl_xor(rs, 16);
            rs += __shfl_xor(rs, 32);
            lr[qt] = lr[qt] * al + rs;
            alpha[qt] = al;
        }
        #pragma unroll
        for (int nt = 0; nt < 8; nt++)
            #pragma unroll
            for (int qt = 0; qt < 2; qt++) {
                float al = alpha[qt];
                ot[nt][qt][0] *= al; ot[nt][qt][1] *= al;
                ot[nt][qt][2] *= al; ot[nt][qt][3] *= al;
            }

        // ---- P^T -> wave-private LDS [q][key]: packed b64 writes, b128 reads ----
        #pragma unroll
        for (int qt = 0; qt < 2; qt++)
            #pragma unroll
            for (int nt = 0; nt < 4; nt++) {
                ushort4 pk;
                pk.x = bf16_rne(scr[nt][qt][0]);
                pk.y = bf16_rne(scr[nt][qt][1]);
                pk.z = bf16_rne(scr[nt][qt][2]);
                pk.w = bf16_rne(scr[nt][qt][3]);
                *(ushort4*)&pw[(qt * 16 + l16) * LDPP + nt * 16 + quad * 4] = pk;
            }
        bf16x8 pf[2][2];
        #pragma unroll
        for (int qt = 0; qt < 2; qt++)
            #pragma unroll
            for (int ks = 0; ks < 2; ks++)
                pf[qt][ks] = *(const bf16x8*)&pw[(qt * 16 + l16) * LDPP + ks * 32 + quad * 8];

        // ---- PV: A = V^T fragment from LDS chunk ks ([128 d][32 k]) ----
        #pragma unroll
        for (int ks = 0; ks < 2; ks++) {
            #pragma unroll
            for (int ntd = 0; ntd < 8; ntd++) {
                bf16x8 vf = *(const bf16x8*)&cur[16384 + ks * 4096 + (ntd * 16 + l16) * 32 + quad * 8];
                #pragma unroll
                for (int qt = 0; qt < 2; qt++)
                    ot[ntd][qt] = mfma16(vf, pf[qt][ks], ot[ntd][qt]);
            }
        }
    }

    // ---- epilogue: O^T/l, packed split-store attn [b*S+token][h*128+d] ----
    #pragma unroll
    for (int qt = 0; qt < 2; qt++) {
        float inv = 1.0f / lr[qt];
        int token = q0 + w * 32 + qt * 16 + l16;
        #pragma unroll
        for (int ntd = 0; ntd < 8; ntd++) {
            int d0 = ntd * 16 + quad * 4;
            size_t idx = (size_t)(b * SS + token) * (NHEADS * HD) + h * HD + d0;
            ushort4 ph, plo;
            #pragma unroll
            for (int r = 0; r < 4; r++) {
                float val = ot[ntd][qt][r] * inv;
                u32 u = __float_as_uint(val);
                u16 hb = (u16)(u >> 16);
                float rr2 = val - __uint_as_float(u & 0xFFFF0000u);
                u16 lb = (u16)(__float_as_uint(rr2) >> 16);
                if (r == 0) { ph.x = hb; plo.x = lb; }
                else if (r == 1) { ph.y = hb; plo.y = lb; }
                else if (r == 2) { ph.z = hb; plo.z = lb; }
                else { ph.w = hb; plo.w = lb; }
            }
            *(ushort4*)(Ao_h + idx) = ph;
            *(ushort4*)(Ao_l + idx) = plo;
        }
    }
}

// ---------------- K3: output projection C = attn @ Wo^T (pre-split bf16 inputs) ----------------
__global__ __launch_bounds__(256) void k_oproj(
    const u16* __restrict__ Ahp, const u16* __restrict__ Alp,
    const u16* __restrict__ Boh, const u16* __restrict__ Bol,
    float* __restrict__ out)
{
    __shared__ u16 sm[16384];   // 4 planes x [128][32]

    const int tid  = threadIdx.x;
    const int w    = tid >> 6;
    const int lane = tid & 63;
    const int quad = lane >> 4;
    const int l16  = lane & 15;
    const int n0 = blockIdx.x * 128;
    const int m0 = blockIdx.y * 128;
    const int KD = NHEADS * HD;   // 4096

    const u16* pb;
    if      (w == 0) pb = Ahp + (size_t)m0 * KD;
    else if (w == 1) pb = Alp + (size_t)m0 * KD;
    else if (w == 2) pb = Boh + (size_t)n0 * KD;
    else             pb = Bol + (size_t)n0 * KD;
    const u16* gsrc = pb + (size_t)(lane >> 2) * KD + (lane & 3) * 8;
    u16* lplane = sm + w * 4096;

    const f32x4 zero4 = {0.f, 0.f, 0.f, 0.f};
    f32x4 acc[2][8];
    #pragma unroll
    for (int i = 0; i < 2; i++)
        #pragma unroll
        for (int j = 0; j < 8; j++) acc[i][j] = zero4;

    for (int kk = 0; kk < KD; kk += 32) {
        __syncthreads();
        #pragma unroll
        for (int c = 0; c < 8; c++)
            gld16(gsrc + (size_t)c * 16 * KD + kk, lplane + c * 512);
        __syncthreads();

        bf16x8 ah[2], al[2];
        #pragma unroll
        for (int mt = 0; mt < 2; mt++) {
            int rr = w * 32 + mt * 16 + l16;
            ah[mt] = *(const bf16x8*)&sm[rr * 32 + quad * 8];
            al[mt] = *(const bf16x8*)&sm[4096 + rr * 32 + quad * 8];
        }
        #pragma unroll
        for (int nt = 0; nt < 8; nt++) {
            int rr = nt * 16 + l16;
            bf16x8 bh = *(const bf16x8*)&sm[8192  + rr * 32 + quad * 8];
            bf16x8 bl = *(const bf16x8*)&sm[12288 + rr * 32 + quad * 8];
            #pragma unroll
            for (int mt = 0; mt < 2; mt++) {
                acc[mt][nt] = mfma16(ah[mt], bh, acc[mt][nt]);
                acc[mt][nt] = mfma16(ah[mt], bl, acc[mt][nt]);
                acc[mt][nt] = mfma16(al[mt], bh, acc[mt][nt]);
            }
        }
    }

    #pragma unroll
    for (int mt = 0; mt < 2; mt++)
        #pragma unroll
        for (int nt = 0; nt < 8; nt++)
            #pragma unroll
            for (int r = 0; r < 4; r++) {
                int mrow = m0 + w * 32 + mt * 16 + quad * 4 + r;
                int ncol = n0 + nt * 16 + l16;
                out[(size_t)mrow * HIDDEN + ncol] = acc[mt][nt][r];
            }
}

extern "C" void kernel_launch(void* const* d_in, const int* in_sizes, int n_in,
                              void* d_out, int out_size, void* d_ws, size_t ws_size,
                              hipStream_t stream)
{
    const float* X  = (const float*)d_in[0];
    const float* Wq = (const float*)d_in[2];
    const float* Wk = (const float*)d_in[3];
    const float* Wv = (const float*)d_in[4];
    const float* Wo = (const float*)d_in[5];

    char* p = (char*)d_ws;
    float* ct = (float*)p;  p += (size_t)SS * 64 * 4;
    float* st = (float*)p;  p += (size_t)SS * 64 * 4;
    u16* Qh = (u16*)p;  p += (size_t)BB * NHEADS * SS * HD * 2;
    u16* Ql = (u16*)p;  p += (size_t)BB * NHEADS * SS * HD * 2;
    u16* Kh = (u16*)p;  p += (size_t)BB * NKV * SS * HD * 2;
    u16* Kl = (u16*)p;  p += (size_t)BB * NKV * SS * HD * 2;
    u16* Vt = (u16*)p;  p += (size_t)BB * NKV * SS * HD * 2;
    u16* Ah_buf = (u16*)p;  p += (size_t)4096 * 4096 * 2;         // Xh, then attn-hi (aliased)
    u16* Al_buf = (u16*)p;  p += (size_t)4096 * 4096 * 2;         // Xl, then attn-lo
    u16* Wh_buf = (u16*)p;  p += (size_t)5120 * 3584 * 2;         // Wqkv-hi, then Wo-hi
    u16* Wl_buf = (u16*)p;  p += (size_t)5120 * 3584 * 2;         // Wqkv-lo, then Wo-lo

    k_rope<<<dim3(SS * 64 / 256), 256, 0, stream>>>(ct, st);
    k_split4<<<dim3(14336), 256, 0, stream>>>(X,  Ah_buf, Al_buf, 3670016);
    k_split4<<<dim3(14336), 256, 0, stream>>>(Wq, Wh_buf, Wl_buf, 3670016);
    k_split4<<<dim3(1792),  256, 0, stream>>>(Wk, Wh_buf + (size_t)4096*3584, Wl_buf + (size_t)4096*3584, 458752);
    k_split4<<<dim3(1792),  256, 0, stream>>>(Wv, Wh_buf + (size_t)4608*3584, Wl_buf + (size_t)4608*3584, 458752);
    k_qkv<<<dim3(40, 32), 256, 0, stream>>>(Ah_buf, Al_buf, Wh_buf, Wl_buf, ct, st, Qh, Ql, Kh, Kl, Vt);
    k_split4<<<dim3(14336), 256, 0, stream>>>(Wo, Wh_buf, Wl_buf, 3670016);
    k_attn<<<dim3(16, NHEADS, BB), 256, 0, stream>>>(Qh, Ql, Kh, Kl, Vt, Ah_buf, Al_buf);
    k_oproj<<<dim3(28, 32), 256, 0, stream>>>(Ah_buf, Al_buf, Wh_buf, Wl_buf, (float*)d_out);
}

// Round 2
// 1353.634 us; speedup vs baseline: 1.1504x; 1.1504x over previous
//
#include <hip/hip_runtime.h>

#define HIDDEN 3584
#define NHEADS 32
#define NKV 4
#define HD 128
#define BB 2
#define SS 2048
#define LDPP 72     // padded u16 row stride for P^T LDS tile (144B: conflict-free b128 reads)

typedef unsigned short u16;
typedef unsigned int   u32;
typedef __bf16 bf16x8 __attribute__((ext_vector_type(8)));
typedef float  f32x4  __attribute__((ext_vector_type(4)));

__device__ __forceinline__ f32x4 mfma16(bf16x8 a, bf16x8 b, f32x4 c) {
    return __builtin_amdgcn_mfma_f32_16x16x32_bf16(a, b, c, 0, 0, 0);
}

// round-to-nearest-even float->bf16 (no NaN inputs in this problem)
__device__ __forceinline__ u16 bf16_rne(float x) {
    u32 u = __float_as_uint(x);
    return (u16)((u + 0x7FFFu + ((u >> 16) & 1u)) >> 16);
}

// split fp32 pair into packed hi-bf16 pair and lo-bf16 pair (truncation split, rel err ~2^-16)
__device__ __forceinline__ void split_pair(float x0, float x1, u32 &hp, u32 &lp) {
    u32 u0 = __float_as_uint(x0), u1 = __float_as_uint(x1);
    hp = (u0 >> 16) | (u1 & 0xFFFF0000u);
    float r0 = x0 - __uint_as_float(u0 & 0xFFFF0000u);
    float r1 = x1 - __uint_as_float(u1 & 0xFFFF0000u);
    lp = (__float_as_uint(r0) >> 16) | (__float_as_uint(r1) & 0xFFFF0000u);
}

// async global->LDS, 16B per lane; dst is wave-uniform base, lane i lands at dst + i*16B
__device__ __forceinline__ void gld16(const u16* g, const u16* l) {
    __builtin_amdgcn_global_load_lds(
        (const __attribute__((address_space(1))) void*)(uintptr_t)(const void*)g,
        (__attribute__((address_space(3))) void*)(uintptr_t)(const void*)l,
        16, 0, 0);
}

// ---------------- K0: RoPE cos/sin tables [S][64] ----------------
__global__ void k_rope(float* __restrict__ ct, float* __restrict__ st) {
    int i = blockIdx.x * 256 + threadIdx.x;   // 2048*64 entries
    int s = i >> 6, j = i & 63;
    float invf = exp2f(-(float)j * (19.931568569324174f / 64.0f));
    float a = (float)s * invf;
    ct[i] = cosf(a);
    st[i] = sinf(a);
}

// ---------------- K0b: fp32 -> (hi,lo) bf16 plane split, 4 elems/thread ----------------
__global__ __launch_bounds__(256) void k_split4(
    const float* __restrict__ in, u16* __restrict__ hi, u16* __restrict__ lo, int n4)
{
    int i = blockIdx.x * 256 + threadIdx.x;
    if (i >= n4) return;
    float4 v = ((const float4*)in)[i];
    u32 h0, l0, h1, l1;
    split_pair(v.x, v.y, h0, l0);
    split_pair(v.z, v.w, h1, l1);
    ((uint2*)hi)[i] = make_uint2(h0, h1);
    ((uint2*)lo)[i] = make_uint2(l0, l1);
}

// ---------------- K1: fused QKV projection + RoPE (pre-split bf16 inputs) ----------------
__global__ __launch_bounds__(256) void k_qkv(
    const u16* __restrict__ Xh, const u16* __restrict__ Xl,
    const u16* __restrict__ Wh, const u16* __restrict__ Wl,
    const float* __restrict__ ct, const float* __restrict__ st,
    u16* __restrict__ Qh, u16* __restrict__ Ql,
    u16* __restrict__ Kh, u16* __restrict__ Kl,
    u16* __restrict__ Vt)
{
    __shared__ u16 sm[16640];   // 4 planes x [128][32] = 16384 u16; V-transpose reuse needs 16640

    const int tid  = threadIdx.x;
    const int w    = tid >> 6;
    const int lane = tid & 63;
    const int quad = lane >> 4;
    const int l16  = lane & 15;
    const int ntb  = blockIdx.x;
    const int m0   = blockIdx.y * 128;
    const int n0   = ntb * 128;

    const u16* pb;
    if      (w == 0) pb = Xh + (size_t)m0 * HIDDEN;
    else if (w == 1) pb = Xl + (size_t)m0 * HIDDEN;
    else if (w == 2) pb = Wh + (size_t)n0 * HIDDEN;
    else             pb = Wl + (size_t)n0 * HIDDEN;
    const u16* gsrc = pb + (size_t)(lane >> 2) * HIDDEN + (lane & 3) * 8;
    u16* lplane = sm + w * 4096;

    const f32x4 zero4 = {0.f, 0.f, 0.f, 0.f};
    f32x4 acc[2][8];
    #pragma unroll
    for (int i = 0; i < 2; i++)
        #pragma unroll
        for (int j = 0; j < 8; j++) acc[i][j] = zero4;

    for (int kk = 0; kk < HIDDEN; kk += 32) {
        __syncthreads();
        #pragma unroll
        for (int c = 0; c < 8; c++)
            gld16(gsrc + (size_t)c * 16 * HIDDEN + kk, lplane + c * 512);
        __syncthreads();

        bf16x8 ah[2], al[2];
        #pragma unroll
        for (int mt = 0; mt < 2; mt++) {
            int rr = w * 32 + mt * 16 + l16;
            ah[mt] = *(const bf16x8*)&sm[rr * 32 + quad * 8];
            al[mt] = *(const bf16x8*)&sm[4096 + rr * 32 + quad * 8];
        }
        #pragma unroll
        for (int nt = 0; nt < 8; nt++) {
            int rr = nt * 16 + l16;
            bf16x8 bh = *(const bf16x8*)&sm[8192  + rr * 32 + quad * 8];
            bf16x8 bl = *(const bf16x8*)&sm[12288 + rr * 32 + quad * 8];
            #pragma unroll
            for (int mt = 0; mt < 2; mt++) {
                acc[mt][nt] = mfma16(ah[mt], bh, acc[mt][nt]);
                acc[mt][nt] = mfma16(ah[mt], bl, acc[mt][nt]);
                acc[mt][nt] = mfma16(al[mt], bh, acc[mt][nt]);
            }
        }
    }

    const int b  = m0 / SS;
    const int s0 = m0 % SS;
    int region;
    if (ntb < 32)      region = 0;
    else if (ntb < 36) region = 1;
    else               region = 2;

    if (region < 2) {
        u16* dH = (region == 0) ? Qh : Kh;
        u16* dL = (region == 0) ? Ql : Kl;
        const int head   = (region == 0) ? ntb : (ntb - 32);
        const int nheads = (region == 0) ? NHEADS : NKV;
        const float qsc  = (region == 0) ? 0.08838834764831845f : 1.0f;
        #pragma unroll
        for (int mt = 0; mt < 2; mt++) {
            #pragma unroll
            for (int r = 0; r < 4; r++) {
                int s = s0 + w * 32 + mt * 16 + quad * 4 + r;
                const float* cr = ct + s * 64;
                const float* sr = st + s * 64;
                #pragma unroll
                for (int nt = 0; nt < 8; nt++) {
                    int d  = nt * 16 + l16;
                    int jj = (nt & 3) * 16 + l16;
                    float c = cr[jj], sn = sr[jj];
                    float v = acc[mt][nt][r];
                    float p = acc[mt][nt ^ 4][r];
                    float o = (nt < 4) ? (v * c - p * sn) : (v * c + p * sn);
                    o *= qsc;
                    size_t idx = ((size_t)(b * nheads + head) * SS + s) * HD + d;
                    u32 u = __float_as_uint(o);
                    dH[idx] = (u16)(u >> 16);
                    float rr2 = o - __uint_as_float(u & 0xFFFF0000u);
                    dL[idx] = (u16)(__float_as_uint(rr2) >> 16);
                }
            }
        }
    } else {
        __syncthreads();
        u16* tb = sm;   // 128 x 130
        #pragma unroll
        for (int mt = 0; mt < 2; mt++)
            #pragma unroll
            for (int nt = 0; nt < 8; nt++)
                #pragma unroll
                for (int r = 0; r < 4; r++) {
                    int rl = w * 32 + mt * 16 + quad * 4 + r;
                    int d  = nt * 16 + l16;
                    tb[rl * 130 + d] = bf16_rne(acc[mt][nt][r]);
                }
        __syncthreads();
        const int hv = ntb - 36;
        const int d = tid >> 1, half = tid & 1;
        u16* dst = Vt + ((size_t)(b * NKV + hv) * HD + d) * SS + s0 + half * 64;
        #pragma unroll
        for (int j0 = 0; j0 < 64; j0 += 4) {
            ushort4 vv;
            vv.x = tb[(half * 64 + j0 + 0) * 130 + d];
            vv.y = tb[(half * 64 + j0 + 1) * 130 + d];
            vv.z = tb[(half * 64 + j0 + 2) * 130 + d];
            vv.w = tb[(half * 64 + j0 + 3) * 130 + d];
            *(ushort4*)(dst + j0) = vv;
        }
    }
}

// ---------------- K2: flash attention v4 — 8 waves / 256 q-rows per block ----------------
// 512 threads, grid (S/256, NHEADS, B). Wave w owns query rows [w*32, w*32+32). 64 keys/iter.
// KV double-buffered in LDS (shared by all 8 waves -> 2 waves/SIMD for latency hiding).
// Lane-linear staging: fragment reads are cur[... + lane*8] -> conflict-free b128.
// S^T = K·Q^T; softmax per lane-column; P^T wave-private LDS (LDPP=72); O^T = V^T·P^T.
__global__ __launch_bounds__(512, 2) void k_attn(
    const u16* __restrict__ Qh, const u16* __restrict__ Ql,
    const u16* __restrict__ Kh, const u16* __restrict__ Kl,
    const u16* __restrict__ Vt, u16* __restrict__ Ao_h, u16* __restrict__ Ao_l)
{
    // parity p at ls + p*24576 (u16 units): Khi 4x[16rows x 32dims x 4c] | Klo same | V 2x[8seg x 512]
    // P^T at ls + 49152 + w*2304: [32 q][64 key] stride LDPP
    __shared__ u16 ls[67584];   // 135168 B

    const int tid  = threadIdx.x;
    const int w    = tid >> 6;          // 0..7
    const int lane = tid & 63;
    const int quad = lane >> 4;
    const int l16  = lane & 15;
    const int q0 = blockIdx.x * 256, h = blockIdx.y, b = blockIdx.z, hv = h >> 3;

    const u16* qbh = Qh + ((size_t)(b * NHEADS + h) * SS + q0) * HD;
    const u16* qbl = Ql + ((size_t)(b * NHEADS + h) * SS + q0) * HD;
    const u16* kbh = Kh + (size_t)(b * NKV + hv) * SS * HD;
    const u16* kbl = Kl + (size_t)(b * NKV + hv) * SS * HD;
    const u16* vb  = Vt + (size_t)(b * NKV + hv) * HD * SS;

    // Q fragments resident (B-operand of S^T: lane l16 = q-row, k = quad*8+j dims)
    bf16x8 qfh[2][4], qfl[2][4];
    #pragma unroll
    for (int qt = 0; qt < 2; qt++) {
        int row = w * 32 + qt * 16 + l16;
        #pragma unroll
        for (int c = 0; c < 4; c++) {
            qfh[qt][c] = *(const bf16x8*)(qbh + (size_t)row * HD + c * 32 + quad * 8);
            qfl[qt][c] = *(const bf16x8*)(qbl + (size_t)row * HD + c * 32 + quad * 8);
        }
    }

    const f32x4 zero4 = {0.f, 0.f, 0.f, 0.f};
    f32x4 ot[8][2];              // O^T accum: row=dim(quad*4+r within ntd tile), col=q(l16)
    #pragma unroll
    for (int i = 0; i < 8; i++)
        #pragma unroll
        for (int j = 0; j < 2; j++) ot[i][j] = zero4;
    float mr[2] = {-INFINITY, -INFINITY}, lr[2] = {0.f, 0.f};   // per-lane: q = qt*16+l16

    u16* pw = ls + 49152 + w * 2304;

    // stage 48 gld16 (1KB each) for iteration `it` into parity it&1; wave w covers g = w*6..w*6+5
    // lane-linear LDS: within each 512-u16 seg, lane L holds [row L&15][8 cols chosen by L>>4]
    auto stage = [&](int it) {
        u16* base = ls + (it & 1) * 24576;
        int kt64 = it * 64;
        #pragma unroll
        for (int j = 0; j < 6; j++) {
            int g = w * 6 + j;           // wave-uniform
            const u16* gp; u16* lp;
            if (g < 32) {                // K planes: 2 planes x 4 dim-chunks x 4 key-segs
                int plane = g >> 4, c = (g >> 2) & 3, seg = g & 3;
                const u16* kb = plane ? kbl : kbh;
                gp = kb + (size_t)(kt64 + seg * 16 + l16) * HD + c * 32 + quad * 8;
                lp = base + plane * 8192 + c * 2048 + seg * 512 + lane * 8;
            } else {                     // V: 2 key-chunks x 8 d-segs of [16 d][32 k]
                int gg = g - 32, ks = gg >> 3, seg = gg & 7;
                gp = vb + (size_t)(seg * 16 + l16) * SS + kt64 + ks * 32 + quad * 8;
                lp = base + 16384 + ks * 4096 + seg * 512 + lane * 8;
            }
            gld16(gp, lp);
        }
    };

    stage(0);

    for (int it = 0; it < SS / 64; it++) {
        __syncthreads();                 // drains own gld16s for iter `it`; syncs LDS visibility
        if (it + 1 < SS / 64) stage(it + 1);

        const u16* cur = ls + (it & 1) * 24576;

        // ---- scores: A = K fragment from LDS (lane-linear: conflict-free) ----
        f32x4 scr[4][2];                 // S^T: [key-subtile nt][q-tile qt]
        #pragma unroll
        for (int i = 0; i < 4; i++)
            #pragma unroll
            for (int j = 0; j < 2; j++) scr[i][j] = zero4;

        __builtin_amdgcn_s_setprio(1);
        #pragma unroll
        for (int c = 0; c < 4; c++) {
            #pragma unroll
            for (int nt = 0; nt < 4; nt++) {
                int off = c * 2048 + nt * 512 + lane * 8;
                bf16x8 kh8 = *(const bf16x8*)&cur[off];
                bf16x8 kl8 = *(const bf16x8*)&cur[8192 + off];
                #pragma unroll
                for (int qt = 0; qt < 2; qt++) {
                    scr[nt][qt] = mfma16(kh8, qfh[qt][c], scr[nt][qt]);
                    scr[nt][qt] = mfma16(kh8, qfl[qt][c], scr[nt][qt]);
                    scr[nt][qt] = mfma16(kl8, qfh[qt][c], scr[nt][qt]);
                }
            }
        }
        __builtin_amdgcn_s_setprio(0);

        // ---- online softmax: stats per lane column (q = qt*16+l16) ----
        float alpha[2];
        #pragma unroll
        for (int qt = 0; qt < 2; qt++) {
            f32x4 m4 = scr[0][qt];
            #pragma unroll
            for (int nt = 1; nt < 4; nt++) m4 = __builtin_elementwise_max(m4, scr[nt][qt]);
            float rm = fmaxf(fmaxf(m4[0], m4[1]), fmaxf(m4[2], m4[3]));
            rm = fmaxf(rm, __shfl_xor(rm, 16));
            rm = fmaxf(rm, __shfl_xor(rm, 32));
            float mn = fmaxf(mr[qt], rm);
            float al = __expf(mr[qt] - mn);
            mr[qt] = mn;
            float rs = 0.f;
            #pragma unroll
            for (int nt = 0; nt < 4; nt++)
                #pragma unroll
                for (int r = 0; r < 4; r++) {
                    float p = __expf(scr[nt][qt][r] - mn);
                    scr[nt][qt][r] = p;
                    rs += p;
                }
            rs += __shfl_xor(rs, 16);
            rs += __shfl_xor(rs, 32);
            lr[qt] = lr[qt] * al + rs;
            alpha[qt] = al;
        }
        #pragma unroll
        for (int nt = 0; nt < 8; nt++)
            #pragma unroll
            for (int qt = 0; qt < 2; qt++) {
                float al = alpha[qt];
                ot[nt][qt][0] *= al; ot[nt][qt][1] *= al;
                ot[nt][qt][2] *= al; ot[nt][qt][3] *= al;
            }

        // ---- P^T -> wave-private LDS [q][key]: packed b64 writes, b128 reads ----
        #pragma unroll
        for (int qt = 0; qt < 2; qt++)
            #pragma unroll
            for (int nt = 0; nt < 4; nt++) {
                ushort4 pk;
                pk.x = bf16_rne(scr[nt][qt][0]);
                pk.y = bf16_rne(scr[nt][qt][1]);
                pk.z = bf16_rne(scr[nt][qt][2]);
                pk.w = bf16_rne(scr[nt][qt][3]);
                *(ushort4*)&pw[(qt * 16 + l16) * LDPP + nt * 16 + quad * 4] = pk;
            }
        bf16x8 pf[2][2];
        #pragma unroll
        for (int qt = 0; qt < 2; qt++)
            #pragma unroll
            for (int ks = 0; ks < 2; ks++)
                pf[qt][ks] = *(const bf16x8*)&pw[(qt * 16 + l16) * LDPP + ks * 32 + quad * 8];

        // ---- PV: A = V^T fragment from LDS chunk ks (lane-linear) ----
        __builtin_amdgcn_s_setprio(1);
        #pragma unroll
        for (int ks = 0; ks < 2; ks++) {
            #pragma unroll
            for (int ntd = 0; ntd < 8; ntd++) {
                bf16x8 vf = *(const bf16x8*)&cur[16384 + ks * 4096 + ntd * 512 + lane * 8];
                #pragma unroll
                for (int qt = 0; qt < 2; qt++)
                    ot[ntd][qt] = mfma16(vf, pf[qt][ks], ot[ntd][qt]);
            }
        }
        __builtin_amdgcn_s_setprio(0);
    }

    // ---- epilogue: O^T/l, packed split-store attn [b*S+token][h*128+d] ----
    #pragma unroll
    for (int qt = 0; qt < 2; qt++) {
        float inv = 1.0f / lr[qt];
        int token = q0 + w * 32 + qt * 16 + l16;
        #pragma unroll
        for (int ntd = 0; ntd < 8; ntd++) {
            int d0 = ntd * 16 + quad * 4;
            size_t idx = (size_t)(b * SS + token) * (NHEADS * HD) + h * HD + d0;
            ushort4 ph, plo;
            #pragma unroll
            for (int r = 0; r < 4; r++) {
                float val = ot[ntd][qt][r] * inv;
                u32 u = __float_as_uint(val);
                u16 hb = (u16)(u >> 16);
                float rr2 = val - __uint_as_float(u & 0xFFFF0000u);
                u16 lb = (u16)(__float_as_uint(rr2) >> 16);
                if (r == 0) { ph.x = hb; plo.x = lb; }
                else if (r == 1) { ph.y = hb; plo.y = lb; }
                else if (r == 2) { ph.z = hb; plo.z = lb; }
                else { ph.w = hb; plo.w = lb; }
            }
            *(ushort4*)(Ao_h + idx) = ph;
            *(ushort4*)(Ao_l + idx) = plo;
        }
    }
}

// ---------------- K3: output projection C = attn @ Wo^T (pre-split bf16 inputs) ----------------
__global__ __launch_bounds__(256) void k_oproj(
    const u16* __restrict__ Ahp, const u16* __restrict__ Alp,
    const u16* __restrict__ Boh, const u16* __restrict__ Bol,
    float* __restrict__ out)
{
    __shared__ u16 sm[16384];   // 4 planes x [128][32]

    const int tid  = threadIdx.x;
    const int w    = tid >> 6;
    const int lane = tid & 63;
    const int quad = lane >> 4;
    const int l16  = lane & 15;
    const int n0 = blockIdx.x * 128;
    const int m0 = blockIdx.y * 128;
    const int KD = NHEADS * HD;   // 4096

    const u16* pb;
    if      (w == 0) pb = Ahp + (size_t)m0 * KD;
    else if (w == 1) pb = Alp + (size_t)m0 * KD;
    else if (w == 2) pb = Boh + (size_t)n0 * KD;
    else             pb = Bol + (size_t)n0 * KD;
    const u16* gsrc = pb + (size_t)(lane >> 2) * KD + (lane & 3) * 8;
    u16* lplane = sm + w * 4096;

    const f32x4 zero4 = {0.f, 0.f, 0.f, 0.f};
    f32x4 acc[2][8];
    #pragma unroll
    for (int i = 0; i < 2; i++)
        #pragma unroll
        for (int j = 0; j < 8; j++) acc[i][j] = zero4;

    for (int kk = 0; kk < KD; kk += 32) {
        __syncthreads();
        #pragma unroll
        for (int c = 0; c < 8; c++)
            gld16(gsrc + (size_t)c * 16 * KD + kk, lplane + c * 512);
        __syncthreads();

        bf16x8 ah[2], al[2];
        #pragma unroll
        for (int mt = 0; mt < 2; mt++) {
            int rr = w * 32 + mt * 16 + l16;
            ah[mt] = *(const bf16x8*)&sm[rr * 32 + quad * 8];
            al[mt] = *(const bf16x8*)&sm[4096 + rr * 32 + quad * 8];
        }
        #pragma unroll
        for (int nt = 0; nt < 8; nt++) {
            int rr = nt * 16 + l16;
            bf16x8 bh = *(const bf16x8*)&sm[8192  + rr * 32 + quad * 8];
            bf16x8 bl = *(const bf16x8*)&sm[12288 + rr * 32 + quad * 8];
            #pragma unroll
            for (int mt = 0; mt < 2; mt++) {
                acc[mt][nt] = mfma16(ah[mt], bh, acc[mt][nt]);
                acc[mt][nt] = mfma16(ah[mt], bl, acc[mt][nt]);
                acc[mt][nt] = mfma16(al[mt], bh, acc[mt][nt]);
            }
        }
    }

    #pragma unroll
    for (int mt = 0; mt < 2; mt++)
        #pragma unroll
        for (int nt = 0; nt < 8; nt++)
            #pragma unroll
            for (int r = 0; r < 4; r++) {
                int mrow = m0 + w * 32 + mt * 16 + quad * 4 + r;
                int ncol = n0 + nt * 16 + l16;
                out[(size_t)mrow * HIDDEN + ncol] = acc[mt][nt][r];
            }
}

extern "C" void kernel_launch(void* const* d_in, const int* in_sizes, int n_in,
                              void* d_out, int out_size, void* d_ws, size_t ws_size,
                              hipStream_t stream)
{
    const float* X  = (const float*)d_in[0];
    const float* Wq = (const float*)d_in[2];
    const float* Wk = (const float*)d_in[3];
    const float* Wv = (const float*)d_in[4];
    const float* Wo = (const float*)d_in[5];

    char* p = (char*)d_ws;
    float* ct = (float*)p;  p += (size_t)SS * 64 * 4;
    float* st = (float*)p;  p += (size_t)SS * 64 * 4;
    u16* Qh = (u16*)p;  p += (size_t)BB * NHEADS * SS * HD * 2;
    u16* Ql = (u16*)p;  p += (size_t)BB * NHEADS * SS * HD * 2;
    u16* Kh = (u16*)p;  p += (size_t)BB * NKV * SS * HD * 2;
    u16* Kl = (u16*)p;  p += (size_t)BB * NKV * SS * HD * 2;
    u16* Vt = (u16*)p;  p += (size_t)BB * NKV * SS * HD * 2;
    u16* Ah_buf = (u16*)p;  p += (size_t)4096 * 4096 * 2;         // Xh, then attn-hi (aliased)
    u16* Al_buf = (u16*)p;  p += (size_t)4096 * 4096 * 2;         // Xl, then attn-lo
    u16* Wh_buf = (u16*)p;  p += (size_t)5120 * 3584 * 2;         // Wqkv-hi, then Wo-hi
    u16* Wl_buf = (u16*)p;  p += (size_t)5120 * 3584 * 2;         // Wqkv-lo, then Wo-lo

    k_rope<<<dim3(SS * 64 / 256), 256, 0, stream>>>(ct, st);
    k_split4<<<dim3(14336), 256, 0, stream>>>(X,  Ah_buf, Al_buf, 3670016);
    k_split4<<<dim3(14336), 256, 0, stream>>>(Wq, Wh_buf, Wl_buf, 3670016);
    k_split4<<<dim3(1792),  256, 0, stream>>>(Wk, Wh_buf + (size_t)4096*3584, Wl_buf + (size_t)4096*3584, 458752);
    k_split4<<<dim3(1792),  256, 0, stream>>>(Wv, Wh_buf + (size_t)4608*3584, Wl_buf + (size_t)4608*3584, 458752);
    k_qkv<<<dim3(40, 32), 256, 0, stream>>>(Ah_buf, Al_buf, Wh_buf, Wl_buf, ct, st, Qh, Ql, Kh, Kl, Vt);
    k_split4<<<dim3(14336), 256, 0, stream>>>(Wo, Wh_buf, Wl_buf, 3670016);
    k_attn<<<dim3(8, NHEADS, BB), 512, 0, stream>>>(Qh, Ql, Kh, Kl, Vt, Ah_buf, Al_buf);
    k_oproj<<<dim3(28, 32), 256, 0, stream>>>(Ah_buf, Al_buf, Wh_buf, Wl_buf, (float*)d_out);
}

// Round 3
// 1239.638 us; speedup vs baseline: 1.2562x; 1.0920x over previous
//
#include <hip/hip_runtime.h>

#define HIDDEN 3584
#define NHEADS 32
#define NKV 4
#define HD 128
#define BB 2
#define SS 2048
#define LDPP 72     // padded u16 row stride for P^T LDS tile (144B: conflict-free b128 reads)

typedef unsigned short u16;
typedef unsigned int   u32;
typedef __bf16 bf16x8 __attribute__((ext_vector_type(8)));
typedef float  f32x4  __attribute__((ext_vector_type(4)));

__device__ __forceinline__ f32x4 mfma16(bf16x8 a, bf16x8 b, f32x4 c) {
    return __builtin_amdgcn_mfma_f32_16x16x32_bf16(a, b, c, 0, 0, 0);
}

// round-to-nearest-even float->bf16 (no NaN inputs in this problem)
__device__ __forceinline__ u16 bf16_rne(float x) {
    u32 u = __float_as_uint(x);
    return (u16)((u + 0x7FFFu + ((u >> 16) & 1u)) >> 16);
}

// split fp32 pair into packed hi-bf16 pair and lo-bf16 pair (truncation split, rel err ~2^-16)
__device__ __forceinline__ void split_pair(float x0, float x1, u32 &hp, u32 &lp) {
    u32 u0 = __float_as_uint(x0), u1 = __float_as_uint(x1);
    hp = (u0 >> 16) | (u1 & 0xFFFF0000u);
    float r0 = x0 - __uint_as_float(u0 & 0xFFFF0000u);
    float r1 = x1 - __uint_as_float(u1 & 0xFFFF0000u);
    lp = (__float_as_uint(r0) >> 16) | (__float_as_uint(r1) & 0xFFFF0000u);
}

// async global->LDS, 16B per lane; dst is wave-uniform base, lane i lands at dst + i*16B
__device__ __forceinline__ void gld16(const u16* g, const u16* l) {
    __builtin_amdgcn_global_load_lds(
        (const __attribute__((address_space(1))) void*)(uintptr_t)(const void*)g,
        (__attribute__((address_space(3))) void*)(uintptr_t)(const void*)l,
        16, 0, 0);
}

// ---------------- K0: RoPE cos/sin tables [S][64] ----------------
__global__ void k_rope(float* __restrict__ ct, float* __restrict__ st) {
    int i = blockIdx.x * 256 + threadIdx.x;   // 2048*64 entries
    int s = i >> 6, j = i & 63;
    float invf = exp2f(-(float)j * (19.931568569324174f / 64.0f));
    float a = (float)s * invf;
    ct[i] = cosf(a);
    st[i] = sinf(a);
}

// ---------------- K0b: fp32 -> (hi,lo) bf16 plane split, 4 elems/thread ----------------
__global__ __launch_bounds__(256) void k_split4(
    const float* __restrict__ in, u16* __restrict__ hi, u16* __restrict__ lo, int n4)
{
    int i = blockIdx.x * 256 + threadIdx.x;
    if (i >= n4) return;
    float4 v = ((const float4*)in)[i];
    u32 h0, l0, h1, l1;
    split_pair(v.x, v.y, h0, l0);
    split_pair(v.z, v.w, h1, l1);
    ((uint2*)hi)[i] = make_uint2(h0, h1);
    ((uint2*)lo)[i] = make_uint2(l0, l1);
}

// ---------------- K1: fused QKV projection + RoPE (pre-split bf16 inputs) ----------------
// v2: pipelined double-buffered staging (1 barrier/step) + XOR-swizzled fragment layout.
// Swizzle: reader uses quad' = quad ^ ((l16>>1)&3); writer permutes GLOBAL col per lane
// (qx = (lane&3) ^ ((lane>>3)&3)) so gld16's linear LDS dest matches (both-sides rule).
__global__ __launch_bounds__(256) void k_qkv(
    const u16* __restrict__ Xh, const u16* __restrict__ Xl,
    const u16* __restrict__ Wh, const u16* __restrict__ Wl,
    const float* __restrict__ ct, const float* __restrict__ st,
    u16* __restrict__ Qh, u16* __restrict__ Ql,
    u16* __restrict__ Kh, u16* __restrict__ Kl,
    u16* __restrict__ Vt)
{
    __shared__ u16 sm[32768];   // 2 parities x 4 planes x [128][32]; V-transpose reuse spans base

    const int tid  = threadIdx.x;
    const int w    = tid >> 6;
    const int lane = tid & 63;
    const int quad = lane >> 4;
    const int l16  = lane & 15;
    const int ntb  = blockIdx.x;
    const int m0   = blockIdx.y * 128;
    const int n0   = ntb * 128;

    const u16* pb;
    if      (w == 0) pb = Xh + (size_t)m0 * HIDDEN;
    else if (w == 1) pb = Xl + (size_t)m0 * HIDDEN;
    else if (w == 2) pb = Wh + (size_t)n0 * HIDDEN;
    else             pb = Wl + (size_t)n0 * HIDDEN;
    const int qx = (lane & 3) ^ ((lane >> 3) & 3);      // pre-swizzled global col
    const u16* gsrc = pb + (size_t)(lane >> 2) * HIDDEN + qx * 8;

    const int qsw = (quad ^ ((l16 >> 1) & 3)) * 8;      // swizzled fragment col offset (u16)

    auto stage = [&](int step) {
        u16* dst = sm + (step & 1) * 16384 + w * 4096;
        const u16* g = gsrc + step * 32;
        #pragma unroll
        for (int c = 0; c < 8; c++)
            gld16(g + (size_t)c * 16 * HIDDEN, dst + c * 512);
    };

    const f32x4 zero4 = {0.f, 0.f, 0.f, 0.f};
    f32x4 acc[2][8];
    #pragma unroll
    for (int i = 0; i < 2; i++)
        #pragma unroll
        for (int j = 0; j < 8; j++) acc[i][j] = zero4;

    stage(0);

    for (int step = 0; step < HIDDEN / 32; step++) {
        __syncthreads();                         // drains own gld16s for this parity
        if (step + 1 < HIDDEN / 32) stage(step + 1);

        const u16* buf = sm + (step & 1) * 16384;

        bf16x8 ah[2], al[2];
        #pragma unroll
        for (int mt = 0; mt < 2; mt++) {
            int so = (w * 2 + mt) * 512 + l16 * 32 + qsw;
            ah[mt] = *(const bf16x8*)&buf[so];
            al[mt] = *(const bf16x8*)&buf[4096 + so];
        }
        #pragma unroll
        for (int nt = 0; nt < 8; nt++) {
            int so = nt * 512 + l16 * 32 + qsw;
            bf16x8 bh = *(const bf16x8*)&buf[8192  + so];
            bf16x8 bl = *(const bf16x8*)&buf[12288 + so];
            #pragma unroll
            for (int mt = 0; mt < 2; mt++) {
                acc[mt][nt] = mfma16(ah[mt], bh, acc[mt][nt]);
                acc[mt][nt] = mfma16(ah[mt], bl, acc[mt][nt]);
                acc[mt][nt] = mfma16(al[mt], bh, acc[mt][nt]);
            }
        }
    }

    const int b  = m0 / SS;
    const int s0 = m0 % SS;
    int region;
    if (ntb < 32)      region = 0;
    else if (ntb < 36) region = 1;
    else               region = 2;

    if (region < 2) {
        u16* dH = (region == 0) ? Qh : Kh;
        u16* dL = (region == 0) ? Ql : Kl;
        const int head   = (region == 0) ? ntb : (ntb - 32);
        const int nheads = (region == 0) ? NHEADS : NKV;
        const float qsc  = (region == 0) ? 0.08838834764831845f : 1.0f;
        #pragma unroll
        for (int mt = 0; mt < 2; mt++) {
            #pragma unroll
            for (int r = 0; r < 4; r++) {
                int s = s0 + w * 32 + mt * 16 + quad * 4 + r;
                const float* cr = ct + s * 64;
                const float* sr = st + s * 64;
                #pragma unroll
                for (int nt = 0; nt < 8; nt++) {
                    int d  = nt * 16 + l16;
                    int jj = (nt & 3) * 16 + l16;
                    float c = cr[jj], sn = sr[jj];
                    float v = acc[mt][nt][r];
                    float p = acc[mt][nt ^ 4][r];
                    float o = (nt < 4) ? (v * c - p * sn) : (v * c + p * sn);
                    o *= qsc;
                    size_t idx = ((size_t)(b * nheads + head) * SS + s) * HD + d;
                    u32 u = __float_as_uint(o);
                    dH[idx] = (u16)(u >> 16);
                    float rr2 = o - __uint_as_float(u & 0xFFFF0000u);
                    dL[idx] = (u16)(__float_as_uint(rr2) >> 16);
                }
            }
        }
    } else {
        __syncthreads();
        u16* tb = sm;   // 128 x 130 (spans parity buffers; safe after barrier)
        #pragma unroll
        for (int mt = 0; mt < 2; mt++)
            #pragma unroll
            for (int nt = 0; nt < 8; nt++)
                #pragma unroll
                for (int r = 0; r < 4; r++) {
                    int rl = w * 32 + mt * 16 + quad * 4 + r;
                    int d  = nt * 16 + l16;
                    tb[rl * 130 + d] = bf16_rne(acc[mt][nt][r]);
                }
        __syncthreads();
        const int hv = ntb - 36;
        const int d = tid >> 1, half = tid & 1;
        u16* dst = Vt + ((size_t)(b * NKV + hv) * HD + d) * SS + s0 + half * 64;
        #pragma unroll
        for (int j0 = 0; j0 < 64; j0 += 4) {
            ushort4 vv;
            vv.x = tb[(half * 64 + j0 + 0) * 130 + d];
            vv.y = tb[(half * 64 + j0 + 1) * 130 + d];
            vv.z = tb[(half * 64 + j0 + 2) * 130 + d];
            vv.w = tb[(half * 64 + j0 + 3) * 130 + d];
            *(ushort4*)(dst + j0) = vv;
        }
    }
}

// ---------------- K2: flash attention v4 — 8 waves / 256 q-rows per block ----------------
// 512 threads, grid (S/256, NHEADS, B). Wave w owns query rows [w*32, w*32+32). 64 keys/iter.
// KV double-buffered in LDS (shared by all 8 waves -> 2 waves/SIMD for latency hiding).
// Lane-linear staging: fragment reads are cur[... + lane*8] -> conflict-free b128.
// S^T = K·Q^T; softmax per lane-column; P^T wave-private LDS (LDPP=72); O^T = V^T·P^T.
__global__ __launch_bounds__(512, 2) void k_attn(
    const u16* __restrict__ Qh, const u16* __restrict__ Ql,
    const u16* __restrict__ Kh, const u16* __restrict__ Kl,
    const u16* __restrict__ Vt, u16* __restrict__ Ao_h, u16* __restrict__ Ao_l)
{
    // parity p at ls + p*24576 (u16 units): Khi 4x[16rows x 32dims x 4c] | Klo same | V 2x[8seg x 512]
    // P^T at ls + 49152 + w*2304: [32 q][64 key] stride LDPP
    __shared__ u16 ls[67584];   // 135168 B

    const int tid  = threadIdx.x;
    const int w    = tid >> 6;          // 0..7
    const int lane = tid & 63;
    const int quad = lane >> 4;
    const int l16  = lane & 15;
    const int q0 = blockIdx.x * 256, h = blockIdx.y, b = blockIdx.z, hv = h >> 3;

    const u16* qbh = Qh + ((size_t)(b * NHEADS + h) * SS + q0) * HD;
    const u16* qbl = Ql + ((size_t)(b * NHEADS + h) * SS + q0) * HD;
    const u16* kbh = Kh + (size_t)(b * NKV + hv) * SS * HD;
    const u16* kbl = Kl + (size_t)(b * NKV + hv) * SS * HD;
    const u16* vb  = Vt + (size_t)(b * NKV + hv) * HD * SS;

    // Q fragments resident (B-operand of S^T: lane l16 = q-row, k = quad*8+j dims)
    bf16x8 qfh[2][4], qfl[2][4];
    #pragma unroll
    for (int qt = 0; qt < 2; qt++) {
        int row = w * 32 + qt * 16 + l16;
        #pragma unroll
        for (int c = 0; c < 4; c++) {
            qfh[qt][c] = *(const bf16x8*)(qbh + (size_t)row * HD + c * 32 + quad * 8);
            qfl[qt][c] = *(const bf16x8*)(qbl + (size_t)row * HD + c * 32 + quad * 8);
        }
    }

    const f32x4 zero4 = {0.f, 0.f, 0.f, 0.f};
    f32x4 ot[8][2];              // O^T accum: row=dim(quad*4+r within ntd tile), col=q(l16)
    #pragma unroll
    for (int i = 0; i < 8; i++)
        #pragma unroll
        for (int j = 0; j < 2; j++) ot[i][j] = zero4;
    float mr[2] = {-INFINITY, -INFINITY}, lr[2] = {0.f, 0.f};   // per-lane: q = qt*16+l16

    u16* pw = ls + 49152 + w * 2304;

    // stage 48 gld16 (1KB each) for iteration `it` into parity it&1; wave w covers g = w*6..w*6+5
    // lane-linear LDS: within each 512-u16 seg, lane L holds [row L&15][8 cols chosen by L>>4]
    auto stage = [&](int it) {
        u16* base = ls + (it & 1) * 24576;
        int kt64 = it * 64;
        #pragma unroll
        for (int j = 0; j < 6; j++) {
            int g = w * 6 + j;           // wave-uniform
            const u16* gp; u16* lp;
            if (g < 32) {                // K planes: 2 planes x 4 dim-chunks x 4 key-segs
                int plane = g >> 4, c = (g >> 2) & 3, seg = g & 3;
                const u16* kb = plane ? kbl : kbh;
                gp = kb + (size_t)(kt64 + seg * 16 + l16) * HD + c * 32 + quad * 8;
                lp = base + plane * 8192 + c * 2048 + seg * 512 + lane * 8;
            } else {                     // V: 2 key-chunks x 8 d-segs of [16 d][32 k]
                int gg = g - 32, ks = gg >> 3, seg = gg & 7;
                gp = vb + (size_t)(seg * 16 + l16) * SS + kt64 + ks * 32 + quad * 8;
                lp = base + 16384 + ks * 4096 + seg * 512 + lane * 8;
            }
            gld16(gp, lp);
        }
    };

    stage(0);

    for (int it = 0; it < SS / 64; it++) {
        __syncthreads();                 // drains own gld16s for iter `it`; syncs LDS visibility
        if (it + 1 < SS / 64) stage(it + 1);

        const u16* cur = ls + (it & 1) * 24576;

        // ---- scores: A = K fragment from LDS (lane-linear: conflict-free) ----
        f32x4 scr[4][2];                 // S^T: [key-subtile nt][q-tile qt]
        #pragma unroll
        for (int i = 0; i < 4; i++)
            #pragma unroll
            for (int j = 0; j < 2; j++) scr[i][j] = zero4;

        __builtin_amdgcn_s_setprio(1);
        #pragma unroll
        for (int c = 0; c < 4; c++) {
            #pragma unroll
            for (int nt = 0; nt < 4; nt++) {
                int off = c * 2048 + nt * 512 + lane * 8;
                bf16x8 kh8 = *(const bf16x8*)&cur[off];
                bf16x8 kl8 = *(const bf16x8*)&cur[8192 + off];
                #pragma unroll
                for (int qt = 0; qt < 2; qt++) {
                    scr[nt][qt] = mfma16(kh8, qfh[qt][c], scr[nt][qt]);
                    scr[nt][qt] = mfma16(kh8, qfl[qt][c], scr[nt][qt]);
                    scr[nt][qt] = mfma16(kl8, qfh[qt][c], scr[nt][qt]);
                }
            }
        }
        __builtin_amdgcn_s_setprio(0);

        // ---- online softmax: stats per lane column (q = qt*16+l16) ----
        float alpha[2];
        #pragma unroll
        for (int qt = 0; qt < 2; qt++) {
            f32x4 m4 = scr[0][qt];
            #pragma unroll
            for (int nt = 1; nt < 4; nt++) m4 = __builtin_elementwise_max(m4, scr[nt][qt]);
            float rm = fmaxf(fmaxf(m4[0], m4[1]), fmaxf(m4[2], m4[3]));
            rm = fmaxf(rm, __shfl_xor(rm, 16));
            rm = fmaxf(rm, __shfl_xor(rm, 32));
            float mn = fmaxf(mr[qt], rm);
            float al = __expf(mr[qt] - mn);
            mr[qt] = mn;
            float rs = 0.f;
            #pragma unroll
            for (int nt = 0; nt < 4; nt++)
                #pragma unroll
                for (int r = 0; r < 4; r++) {
                    float p = __expf(scr[nt][qt][r] - mn);
                    scr[nt][qt][r] = p;
                    rs += p;
                }
            rs += __shfl_xor(rs, 16);
            rs += __shfl_xor(rs, 32);
            lr[qt] = lr[qt] * al + rs;
            alpha[qt] = al;
        }
        #pragma unroll
        for (int nt = 0; nt < 8; nt++)
            #pragma unroll
            for (int qt = 0; qt < 2; qt++) {
                float al = alpha[qt];
                ot[nt][qt][0] *= al; ot[nt][qt][1] *= al;
                ot[nt][qt][2] *= al; ot[nt][qt][3] *= al;
            }

        // ---- P^T -> wave-private LDS [q][key]: packed b64 writes, b128 reads ----
        #pragma unroll
        for (int qt = 0; qt < 2; qt++)
            #pragma unroll
            for (int nt = 0; nt < 4; nt++) {
                ushort4 pk;
                pk.x = bf16_rne(scr[nt][qt][0]);
                pk.y = bf16_rne(scr[nt][qt][1]);
                pk.z = bf16_rne(scr[nt][qt][2]);
                pk.w = bf16_rne(scr[nt][qt][3]);
                *(ushort4*)&pw[(qt * 16 + l16) * LDPP + nt * 16 + quad * 4] = pk;
            }
        bf16x8 pf[2][2];
        #pragma unroll
        for (int qt = 0; qt < 2; qt++)
            #pragma unroll
            for (int ks = 0; ks < 2; ks++)
                pf[qt][ks] = *(const bf16x8*)&pw[(qt * 16 + l16) * LDPP + ks * 32 + quad * 8];

        // ---- PV: A = V^T fragment from LDS chunk ks (lane-linear) ----
        __builtin_amdgcn_s_setprio(1);
        #pragma unroll
        for (int ks = 0; ks < 2; ks++) {
            #pragma unroll
            for (int ntd = 0; ntd < 8; ntd++) {
                bf16x8 vf = *(const bf16x8*)&cur[16384 + ks * 4096 + ntd * 512 + lane * 8];
                #pragma unroll
                for (int qt = 0; qt < 2; qt++)
                    ot[ntd][qt] = mfma16(vf, pf[qt][ks], ot[ntd][qt]);
            }
        }
        __builtin_amdgcn_s_setprio(0);
    }

    // ---- epilogue: O^T/l, packed split-store attn [b*S+token][h*128+d] ----
    #pragma unroll
    for (int qt = 0; qt < 2; qt++) {
        float inv = 1.0f / lr[qt];
        int token = q0 + w * 32 + qt * 16 + l16;
        #pragma unroll
        for (int ntd = 0; ntd < 8; ntd++) {
            int d0 = ntd * 16 + quad * 4;
            size_t idx = (size_t)(b * SS + token) * (NHEADS * HD) + h * HD + d0;
            ushort4 ph, plo;
            #pragma unroll
            for (int r = 0; r < 4; r++) {
                float val = ot[ntd][qt][r] * inv;
                u32 u = __float_as_uint(val);
                u16 hb = (u16)(u >> 16);
                float rr2 = val - __uint_as_float(u & 0xFFFF0000u);
                u16 lb = (u16)(__float_as_uint(rr2) >> 16);
                if (r == 0) { ph.x = hb; plo.x = lb; }
                else if (r == 1) { ph.y = hb; plo.y = lb; }
                else if (r == 2) { ph.z = hb; plo.z = lb; }
                else { ph.w = hb; plo.w = lb; }
            }
            *(ushort4*)(Ao_h + idx) = ph;
            *(ushort4*)(Ao_l + idx) = plo;
        }
    }
}

// ---------------- K3: output projection C = attn @ Wo^T (pre-split bf16 inputs) ----------------
// v2: same pipelined staging + swizzle as k_qkv.
__global__ __launch_bounds__(256) void k_oproj(
    const u16* __restrict__ Ahp, const u16* __restrict__ Alp,
    const u16* __restrict__ Boh, const u16* __restrict__ Bol,
    float* __restrict__ out)
{
    __shared__ u16 sm[32768];   // 2 parities x 4 planes x [128][32]

    const int tid  = threadIdx.x;
    const int w    = tid >> 6;
    const int lane = tid & 63;
    const int quad = lane >> 4;
    const int l16  = lane & 15;
    const int n0 = blockIdx.x * 128;
    const int m0 = blockIdx.y * 128;
    const int KD = NHEADS * HD;   // 4096

    const u16* pb;
    if      (w == 0) pb = Ahp + (size_t)m0 * KD;
    else if (w == 1) pb = Alp + (size_t)m0 * KD;
    else if (w == 2) pb = Boh + (size_t)n0 * KD;
    else             pb = Bol + (size_t)n0 * KD;
    const int qx = (lane & 3) ^ ((lane >> 3) & 3);
    const u16* gsrc = pb + (size_t)(lane >> 2) * KD + qx * 8;

    const int qsw = (quad ^ ((l16 >> 1) & 3)) * 8;

    auto stage = [&](int step) {
        u16* dst = sm + (step & 1) * 16384 + w * 4096;
        const u16* g = gsrc + step * 32;
        #pragma unroll
        for (int c = 0; c < 8; c++)
            gld16(g + (size_t)c * 16 * KD, dst + c * 512);
    };

    const f32x4 zero4 = {0.f, 0.f, 0.f, 0.f};
    f32x4 acc[2][8];
    #pragma unroll
    for (int i = 0; i < 2; i++)
        #pragma unroll
        for (int j = 0; j < 8; j++) acc[i][j] = zero4;

    stage(0);

    for (int step = 0; step < KD / 32; step++) {
        __syncthreads();
        if (step + 1 < KD / 32) stage(step + 1);

        const u16* buf = sm + (step & 1) * 16384;

        bf16x8 ah[2], al[2];
        #pragma unroll
        for (int mt = 0; mt < 2; mt++) {
            int so = (w * 2 + mt) * 512 + l16 * 32 + qsw;
            ah[mt] = *(const bf16x8*)&buf[so];
            al[mt] = *(const bf16x8*)&buf[4096 + so];
        }
        #pragma unroll
        for (int nt = 0; nt < 8; nt++) {
            int so = nt * 512 + l16 * 32 + qsw;
            bf16x8 bh = *(const bf16x8*)&buf[8192  + so];
            bf16x8 bl = *(const bf16x8*)&buf[12288 + so];
            #pragma unroll
            for (int mt = 0; mt < 2; mt++) {
                acc[mt][nt] = mfma16(ah[mt], bh, acc[mt][nt]);
                acc[mt][nt] = mfma16(ah[mt], bl, acc[mt][nt]);
                acc[mt][nt] = mfma16(al[mt], bh, acc[mt][nt]);
            }
        }
    }

    #pragma unroll
    for (int mt = 0; mt < 2; mt++)
        #pragma unroll
        for (int nt = 0; nt < 8; nt++)
            #pragma unroll
            for (int r = 0; r < 4; r++) {
                int mrow = m0 + w * 32 + mt * 16 + quad * 4 + r;
                int ncol = n0 + nt * 16 + l16;
                out[(size_t)mrow * HIDDEN + ncol] = acc[mt][nt][r];
            }
}

extern "C" void kernel_launch(void* const* d_in, const int* in_sizes, int n_in,
                              void* d_out, int out_size, void* d_ws, size_t ws_size,
                              hipStream_t stream)
{
    const float* X  = (const float*)d_in[0];
    const float* Wq = (const float*)d_in[2];
    const float* Wk = (const float*)d_in[3];
    const float* Wv = (const float*)d_in[4];
    const float* Wo = (const float*)d_in[5];

    char* p = (char*)d_ws;
    float* ct = (float*)p;  p += (size_t)SS * 64 * 4;
    float* st = (float*)p;  p += (size_t)SS * 64 * 4;
    u16* Qh = (u16*)p;  p += (size_t)BB * NHEADS * SS * HD * 2;
    u16* Ql = (u16*)p;  p += (size_t)BB * NHEADS * SS * HD * 2;
    u16* Kh = (u16*)p;  p += (size_t)BB * NKV * SS * HD * 2;
    u16* Kl = (u16*)p;  p += (size_t)BB * NKV * SS * HD * 2;
    u16* Vt = (u16*)p;  p += (size_t)BB * NKV * SS * HD * 2;
    u16* Ah_buf = (u16*)p;  p += (size_t)4096 * 4096 * 2;         // Xh, then attn-hi (aliased)
    u16* Al_buf = (u16*)p;  p += (size_t)4096 * 4096 * 2;         // Xl, then attn-lo
    u16* Wh_buf = (u16*)p;  p += (size_t)5120 * 3584 * 2;         // Wqkv-hi, then Wo-hi
    u16* Wl_buf = (u16*)p;  p += (size_t)5120 * 3584 * 2;         // Wqkv-lo, then Wo-lo

    k_rope<<<dim3(SS * 64 / 256), 256, 0, stream>>>(ct, st);
    k_split4<<<dim3(14336), 256, 0, stream>>>(X,  Ah_buf, Al_buf, 3670016);
    k_split4<<<dim3(14336), 256, 0, stream>>>(Wq, Wh_buf, Wl_buf, 3670016);
    k_split4<<<dim3(1792),  256, 0, stream>>>(Wk, Wh_buf + (size_t)4096*3584, Wl_buf + (size_t)4096*3584, 458752);
    k_split4<<<dim3(1792),  256, 0, stream>>>(Wv, Wh_buf + (size_t)4608*3584, Wl_buf + (size_t)4608*3584, 458752);
    k_qkv<<<dim3(40, 32), 256, 0, stream>>>(Ah_buf, Al_buf, Wh_buf, Wl_buf, ct, st, Qh, Ql, Kh, Kl, Vt);
    k_split4<<<dim3(14336), 256, 0, stream>>>(Wo, Wh_buf, Wl_buf, 3670016);
    k_attn<<<dim3(8, NHEADS, BB), 512, 0, stream>>>(Qh, Ql, Kh, Kl, Vt, Ah_buf, Al_buf);
    k_oproj<<<dim3(28, 32), 256, 0, stream>>>(Ah_buf, Al_buf, Wh_buf, Wl_buf, (float*)d_out);
}